// Round 2
// baseline (418.807 us; speedup 1.0000x reference)
//
#include <hip/hip_runtime.h>

// Cross-stitch: out_a = w[c][0][0]*x_a + w[c][0][1]*x_b
//               out_b = w[c][1][0]*x_a + w[c][1][1]*x_b
// Shapes: x_a, x_b : [N=32, C=256, H=64, W=64] fp32, w : [C,2,2] fp32.
// d_out = out_a (N*C*H*W floats) followed by out_b (N*C*H*W floats).
//
// Memory-bound: 536.9 MB irreducible traffic -> ~85 us floor at 6.3 TB/s.
//
// Structure (v2b): grid-stride over (n,c) planes. One plane = 64*64 = 4096
// floats = 1024 f32x4. A 256-thread block processes one plane per
// iteration: 4 f32x4 per thread, 8 loads issued back-to-back before any
// dependent use (MLP for latency hiding); weights are block-uniform ->
// s_load. Grid capped at 2048 blocks (256 CU x 8 blocks/CU); nontemporal
// hints since there is zero reuse (512 MiB stream >> 256 MiB L3).
//
// v2 -> v2b: __builtin_nontemporal_* requires a clang vector type, not
// HIP_vector_type<float,4>; use ext_vector_type(4) float.

typedef float f32x4 __attribute__((ext_vector_type(4)));

#define PLANE_V4 1024        // f32x4 per (n,c) plane
#define CMASK    255         // C-1, C=256

__global__ __launch_bounds__(256) void cross_stitch_kernel(
    const f32x4* __restrict__ xa,
    const f32x4* __restrict__ xb,
    const float* __restrict__ w,   // [C,2,2] flat
    f32x4* __restrict__ oa,
    f32x4* __restrict__ ob,
    int n_planes)
{
    const int tid = threadIdx.x;

    for (int plane = blockIdx.x; plane < n_planes; plane += gridDim.x) {
        const int c = plane & CMASK;          // block-uniform -> SGPR
        const float w00 = w[c * 4 + 0];
        const float w01 = w[c * 4 + 1];
        const float w10 = w[c * 4 + 2];
        const float w11 = w[c * 4 + 3];

        const int base = plane * PLANE_V4 + tid;

        f32x4 a[4], b[4];
#pragma unroll
        for (int k = 0; k < 4; ++k)
            a[k] = __builtin_nontemporal_load(&xa[base + k * 256]);
#pragma unroll
        for (int k = 0; k < 4; ++k)
            b[k] = __builtin_nontemporal_load(&xb[base + k * 256]);

#pragma unroll
        for (int k = 0; k < 4; ++k) {
            f32x4 ra, rb;
#pragma unroll
            for (int j = 0; j < 4; ++j) {
                ra[j] = fmaf(w00, a[k][j], w01 * b[k][j]);
                rb[j] = fmaf(w10, a[k][j], w11 * b[k][j]);
            }
            __builtin_nontemporal_store(ra, &oa[base + k * 256]);
            __builtin_nontemporal_store(rb, &ob[base + k * 256]);
        }
    }
}

extern "C" void kernel_launch(void* const* d_in, const int* in_sizes, int n_in,
                              void* d_out, int out_size, void* d_ws, size_t ws_size,
                              hipStream_t stream) {
    const f32x4* xa = (const f32x4*)d_in[0];
    const f32x4* xb = (const f32x4*)d_in[1];
    const float* w  = (const float*)d_in[2];

    const int n_elem   = in_sizes[0];            // 32*256*64*64 = 33,554,432
    const int n_vec4   = n_elem / 4;             // 8,388,608
    const int n_planes = n_vec4 / PLANE_V4;      // 8192 (n,c) planes

    f32x4* oa = (f32x4*)d_out;
    f32x4* ob = (f32x4*)d_out + n_vec4;

    const int block = 256;
    const int grid  = (n_planes < 2048) ? n_planes : 2048;  // 8 blocks/CU cap
    cross_stitch_kernel<<<grid, block, 0, stream>>>(xa, xb, w, oa, ob, n_planes);
}